// Round 6
// baseline (144.991 us; speedup 1.0000x reference)
//
#include <hip/hip_runtime.h>

typedef _Float16 f16;
typedef _Float16 half8 __attribute__((ext_vector_type(8)));
typedef float floatx4 __attribute__((ext_vector_type(4)));

#define MFMA16(a,b,c) __builtin_amdgcn_mfma_f32_16x16x32_f16((a),(b),(c),0,0,0)
// (1/sqrt(128)) * log2(e)
#define RSL2E 0.12751743f

__device__ __forceinline__ void split2(float x, f16 &h, f16 &l) {
  f16 hh = (f16)x;
  h = hh;
  l = (f16)(x - (float)hh);
}

// ---- LDS staging: rows of 64 halves (128B pitch), XOR-swizzled ----
__device__ __forceinline__ void stage_rows64(const f16* __restrict__ g, int gstride,
                                             f16* lds, int rows, int tid, int nthr) {
  int total = rows * 8;
  for (int idx = tid; idx < total; idx += nthr) {
    int row = idx >> 3, slot = idx & 7;
    float4 v = *(const float4*)(g + (size_t)row * gstride + slot * 8);
    int lofs = ((row << 7) + (slot << 4)) ^ ((row & 7) << 4);
    *(float4*)((char*)lds + lofs) = v;
  }
}
// rows of 128 halves (256B pitch), XOR-swizzled
__device__ __forceinline__ void stage_rows128(const f16* __restrict__ g, int gstride,
                                              f16* lds, int rows, int tid, int nthr) {
  int total = rows * 16;
  for (int idx = tid; idx < total; idx += nthr) {
    int row = idx >> 4, slot = idx & 15;
    float4 v = *(const float4*)(g + (size_t)row * gstride + slot * 8);
    int lofs = ((row << 8) + (slot << 4)) ^ ((row & 7) << 4);
    *(float4*)((char*)lds + lofs) = v;
  }
}
__device__ __forceinline__ half8 fragP128(const f16* lds, int row, int kofs) {
  int ofs = ((row << 7) + (kofs << 1)) ^ ((row & 7) << 4);
  return *(const half8*)((const char*)lds + ofs);
}
__device__ __forceinline__ half8 fragP256(const f16* lds, int row, int kofs) {
  int ofs = ((row << 8) + (kofs << 1)) ^ ((row & 7) << 4);
  return *(const half8*)((const char*)lds + ofs);
}

// ---- split fp32 -> (h,l) f16 pairs, elementwise ----
__global__ void k_split(const float4* __restrict__ in, uint2* __restrict__ outh,
                        uint2* __restrict__ outl, int n4) {
  int stride = gridDim.x * blockDim.x;
  for (int i = blockIdx.x * blockDim.x + threadIdx.x; i < n4; i += stride) {
    float4 v = in[i];
    union { f16 a[4]; uint2 u; } ph, pl;
    split2(v.x, ph.a[0], pl.a[0]);
    split2(v.y, ph.a[1], pl.a[1]);
    split2(v.z, ph.a[2], pl.a[2]);
    split2(v.w, ph.a[3], pl.a[3]);
    outh[i] = ph.u;
    outl[i] = pl.u;
  }
}

// ---- transpose + split the three weight matrices ----
__global__ void k_splitW(const float* __restrict__ Wq, const float* __restrict__ Wkv,
                         const float* __restrict__ Wo,
                         f16* WqTh, f16* WqTl, f16* WkvTh, f16* WkvTl,
                         f16* WoTh, f16* WoTl) {
  int idx = blockIdx.x * 256 + threadIdx.x;
  if (idx >= 65536) return;
  float v; f16 *ph, *pl; int dst;
  if (idx < 16384) {
    int n = idx >> 7, c = idx & 127;
    v = Wq[c * 128 + n]; ph = WqTh; pl = WqTl; dst = idx;
  } else if (idx < 49152) {
    int t = idx - 16384; int n = t >> 7, c = t & 127;
    v = Wkv[c * 256 + n]; ph = WkvTh; pl = WkvTl; dst = t;
  } else {
    int t = idx - 49152; int n = t >> 7, c = t & 127;
    v = Wo[c * 128 + n]; ph = WoTh; pl = WoTl; dst = t;
  }
  f16 h, l; split2(v, h, l);
  ph[dst] = h; pl[dst] = l;
}

// ---- split-f16 GEMM: out[64 rows][128 cols] = A[64][128] * BT[128][128]^T + bias ----
// Output is SINGLE f16 (rounded once). mode 0: row-major [l][c]; mode 1: transposed vT [b][c][l]
__global__ __launch_bounds__(512, 2)
void k_proj(const f16* __restrict__ Ah, const f16* __restrict__ Al,
            const f16* __restrict__ BTh, const f16* __restrict__ BTl,
            const float* __restrict__ bias,
            f16* __restrict__ out, int mode) {
  __shared__ f16 pool[24576];
  f16* sAh = pool;           // [64][64]
  f16* sAl = pool + 4096;
  f16* sBh = pool + 8192;    // [128][64]
  f16* sBl = pool + 16384;
  int tid = threadIdx.x, wave = tid >> 6, lane = tid & 63, lg = lane >> 4, lr = lane & 15;
  int wm = wave >> 2, wn = wave & 3;   // 2 x 4 waves, 32x32 wave tiles
  size_t rowbase = (size_t)blockIdx.x * 64;
  floatx4 zero = {0.f, 0.f, 0.f, 0.f};
  floatx4 acc[2][2] = {{zero, zero}, {zero, zero}};
  for (int cc = 0; cc < 128; cc += 64) {
    __syncthreads();
    stage_rows64(Ah + rowbase * 128 + cc, 128, sAh, 64, tid, 512);
    stage_rows64(Al + rowbase * 128 + cc, 128, sAl, 64, tid, 512);
    stage_rows64(BTh + cc, 128, sBh, 128, tid, 512);
    stage_rows64(BTl + cc, 128, sBl, 128, tid, 512);
    __syncthreads();
    for (int kc = 0; kc < 64; kc += 32) {
      half8 ah[2], al[2];
      for (int fm = 0; fm < 2; fm++) {
        ah[fm] = fragP128(sAh, wm * 32 + fm * 16 + lr, kc + lg * 8);
        al[fm] = fragP128(sAl, wm * 32 + fm * 16 + lr, kc + lg * 8);
      }
      for (int fn = 0; fn < 2; fn++) {
        half8 bh = fragP128(sBh, wn * 32 + fn * 16 + lr, kc + lg * 8);
        half8 bl = fragP128(sBl, wn * 32 + fn * 16 + lr, kc + lg * 8);
        for (int fm = 0; fm < 2; fm++) {
          acc[fm][fn] = MFMA16(ah[fm], bh, acc[fm][fn]);
          acc[fm][fn] = MFMA16(ah[fm], bl, acc[fm][fn]);
          acc[fm][fn] = MFMA16(al[fm], bh, acc[fm][fn]);
        }
      }
    }
  }
  __syncthreads();
  f16* e = pool;          // [64][136] padded, single
  for (int fm = 0; fm < 2; fm++) for (int fn = 0; fn < 2; fn++) {
    int n = wn * 32 + fn * 16 + lr;
    float bs = bias[n];
    for (int jj = 0; jj < 4; jj++) {
      int m = wm * 32 + fm * 16 + lg * 4 + jj;
      e[m * 136 + n] = (f16)(acc[fm][fn][jj] + bs);
    }
  }
  __syncthreads();
  if (mode == 0) {
    for (int idx = tid; idx < 1024; idx += 512) {
      int r = idx >> 4, sl = idx & 15;
      *(float4*)(out + (rowbase + r) * 128 + sl * 8) =
          *(const float4*)((const char*)e + r * 272 + sl * 16);
    }
  } else {
    size_t bidx = rowbase >> 13, lofs = rowbase & 8191;
    for (int idx = tid; idx < 1024; idx += 512) {
      int c = idx >> 3, sl = idx & 7;
      union { f16 a[8]; float4 v; } th;
      for (int t = 0; t < 8; t++) th.a[t] = e[(sl * 8 + t) * 136 + c];
      *(float4*)(out + (bidx * 128 + c) * 8192 + lofs + sl * 8) = th.v;
    }
  }
}

// ---- final projection: out fp32 = attnout(split) * WoT^T + bo ----
__global__ __launch_bounds__(512, 2)
void k_final(const f16* __restrict__ Ah, const f16* __restrict__ Al,
             const f16* __restrict__ BTh, const f16* __restrict__ BTl,
             const float* __restrict__ bias, float* __restrict__ out) {
  __shared__ f16 pool[24576];
  f16* sAh = pool;
  f16* sAl = pool + 4096;
  f16* sBh = pool + 8192;
  f16* sBl = pool + 16384;
  int tid = threadIdx.x, wave = tid >> 6, lane = tid & 63, lg = lane >> 4, lr = lane & 15;
  int wm = wave >> 2, wn = wave & 3;
  size_t rowbase = (size_t)blockIdx.x * 64;
  floatx4 zero = {0.f, 0.f, 0.f, 0.f};
  floatx4 acc[2][2] = {{zero, zero}, {zero, zero}};
  for (int cc = 0; cc < 128; cc += 64) {
    __syncthreads();
    stage_rows64(Ah + rowbase * 128 + cc, 128, sAh, 64, tid, 512);
    stage_rows64(Al + rowbase * 128 + cc, 128, sAl, 64, tid, 512);
    stage_rows64(BTh + cc, 128, sBh, 128, tid, 512);
    stage_rows64(BTl + cc, 128, sBl, 128, tid, 512);
    __syncthreads();
    for (int kc = 0; kc < 64; kc += 32) {
      half8 ah[2], al[2];
      for (int fm = 0; fm < 2; fm++) {
        ah[fm] = fragP128(sAh, wm * 32 + fm * 16 + lr, kc + lg * 8);
        al[fm] = fragP128(sAl, wm * 32 + fm * 16 + lr, kc + lg * 8);
      }
      for (int fn = 0; fn < 2; fn++) {
        half8 bh = fragP128(sBh, wn * 32 + fn * 16 + lr, kc + lg * 8);
        half8 bl = fragP128(sBl, wn * 32 + fn * 16 + lr, kc + lg * 8);
        for (int fm = 0; fm < 2; fm++) {
          acc[fm][fn] = MFMA16(ah[fm], bh, acc[fm][fn]);
          acc[fm][fn] = MFMA16(ah[fm], bl, acc[fm][fn]);
          acc[fm][fn] = MFMA16(al[fm], bh, acc[fm][fn]);
        }
      }
    }
  }
  __syncthreads();
  float* ef = (float*)pool;   // [64][132] padded fp32
  for (int fm = 0; fm < 2; fm++) for (int fn = 0; fn < 2; fn++) {
    int n = wn * 32 + fn * 16 + lr;
    float bs = bias[n];
    for (int jj = 0; jj < 4; jj++) {
      int m = wm * 32 + fm * 16 + lg * 4 + jj;
      ef[m * 132 + n] = acc[fm][fn][jj] + bs;
    }
  }
  __syncthreads();
  for (int idx = tid; idx < 2048; idx += 512) {
    int r = idx >> 5, sl = idx & 31;
    *(float4*)(out + (rowbase + r) * 128 + sl * 4) = *(const float4*)(ef + r * 132 + sl * 4);
  }
}

// ---- U[b][i][c] = (1/512) * sum over disallowed k-blocks of their column sums of v ----
__global__ void k_U(const f16* __restrict__ vT, float* __restrict__ U) {
  int b = blockIdx.x >> 7, c = blockIdx.x & 127;
  int tid = threadIdx.x;
  const f16* r = vT + ((size_t)b * 128 + c) * 8192;
  float s = 0.f;
  const float4* r4 = (const float4*)(r + tid * 32);
  for (int t = 0; t < 4; t++) {
    float4 v = r4[t];
    const f16* a = (const f16*)&v;
    for (int u = 0; u < 8; u++) s += (float)a[u];
  }
  __shared__ float part[256];
  __shared__ float bs[16];
  part[tid] = s;
  __syncthreads();
  if (tid < 16) {
    float t = 0.f;
    for (int u = 0; u < 16; u++) t += part[tid * 16 + u];
    bs[tid] = t;
  }
  __syncthreads();
  if (tid < 16) {
    int i = tid;
    float tot = 0.f;
    for (int j = 0; j < 16; j++) tot += bs[j];
    int j0 = i - 2 < 0 ? 0 : i - 2;
    int j1 = i + 2 > 15 ? 15 : i + 2;
    float win = 0.f;
    for (int j = j0; j <= j1; j++) win += bs[j];
    U[((size_t)b * 16 + i) * 128 + c] = (tot - win) * (1.0f / 512.0f);
  }
}

// ---- pass A: Z[b][i][j][d] = sum_s exp2(RSL2E * (k_d . q_s)), single f16 inputs ----
__global__ __launch_bounds__(512, 4)
void k_passA(const f16* __restrict__ kp, const f16* __restrict__ qp,
             float* __restrict__ Z) {
  int bid = blockIdx.x;
  int wg = (bid & 7) * 80 + (bid >> 3);     // XCD-aware bijective swizzle (640 = 8*80)
  int dchunk = wg & 3; int rest = wg >> 2;
  int slot = rest % 5; int rest2 = rest / 5;
  int i = rest2 & 15; int b = rest2 >> 4;
  int j = i - 2 + slot;
  if (j < 0 || j > 15) return;
  __shared__ f16 sK[16384], sQ[16384];  // 64 KiB -> 2 WG/CU
  int tid = threadIdx.x, wave = tid >> 6, lane = tid & 63, lg = lane >> 4, lr = lane & 15;
  int wm = wave >> 1, wn = wave & 1;   // 4 x 2 waves; wave tile 32(d) x 64(s)
  size_t krow = (size_t)b * 8192 + j * 512 + dchunk * 128;
  stage_rows128(kp + krow * 128, 128, sK, 128, tid, 512);
  float zp[2][4] = {{0.f,0.f,0.f,0.f},{0.f,0.f,0.f,0.f}};
  floatx4 zero = {0.f, 0.f, 0.f, 0.f};
  for (int sc = 0; sc < 4; sc++) {
    __syncthreads();
    size_t qrow = (size_t)b * 8192 + i * 512 + sc * 128;
    stage_rows128(qp + qrow * 128, 128, sQ, 128, tid, 512);
    __syncthreads();
    floatx4 acc[2][4] = {{zero,zero,zero,zero},{zero,zero,zero,zero}};
    for (int kc = 0; kc < 128; kc += 32) {
      half8 ah[2];
      for (int fm = 0; fm < 2; fm++)
        ah[fm] = fragP256(sK, wm * 32 + fm * 16 + lr, kc + lg * 8);
      for (int fn = 0; fn < 4; fn++) {
        half8 bh = fragP256(sQ, wn * 64 + fn * 16 + lr, kc + lg * 8);
        for (int fm = 0; fm < 2; fm++)
          acc[fm][fn] = MFMA16(ah[fm], bh, acc[fm][fn]);
      }
    }
    for (int fm = 0; fm < 2; fm++) for (int fn = 0; fn < 4; fn++)
      for (int jj = 0; jj < 4; jj++)
        zp[fm][jj] += exp2f(acc[fm][fn][jj] * RSL2E);
  }
  // in-wave butterfly over lr (16 s-columns)
  for (int off = 1; off < 16; off <<= 1)
    for (int fm = 0; fm < 2; fm++) for (int jj = 0; jj < 4; jj++)
      zp[fm][jj] += __shfl_xor(zp[fm][jj], off, 64);
  // cross-wave combine of the two wn halves via LDS
  __syncthreads();
  float* sred = (float*)sQ;      // 256 floats
  if (lr == 0) {
    for (int fm = 0; fm < 2; fm++) for (int jj = 0; jj < 4; jj++) {
      int d = wm * 32 + fm * 16 + lg * 4 + jj;
      sred[wn * 128 + d] = zp[fm][jj];
    }
  }
  __syncthreads();
  if (tid < 128) {
    size_t zb = (((size_t)(b * 16 + i) * 16 + j) * 512) + dchunk * 128;
    Z[zb + tid] = sred[tid] + sred[128 + tid];
  }
}

// ---- pass B (restructured): per (b, i, s-tile 64, d-half): partial PV into Pbuf ----
// In-register S^T->E transpose via shfl (no sE LDS round-trip); 2 barriers/iter;
// each wave owns a 32-wide d-slice, partial PV acc2[2][8], cross-wave reduce at end.
__global__ __launch_bounds__(512, 4)
void k_passB(const f16* __restrict__ qp, const f16* __restrict__ kp,
             const f16* __restrict__ vT,
             const float* __restrict__ Z, float* __restrict__ Pbuf) {
  int bid = blockIdx.x;
  int wg = ((bid & 7) << 6) | (bid >> 3);   // XCD-aware bijective swizzle (512 = 8*64)
  int dhalf = wg & 1, st = (wg >> 1) & 7, i = (wg >> 4) & 15, b = wg >> 8;
  __shared__ __align__(16) char pool[81920];
  f16* sQ = (f16*)pool;             // [64 s][128 c], 256B pitch, 16 KB
  f16* sK = (f16*)(pool + 16384);   // [128 d][128 c], 256B pitch, 32 KB
  f16* sV = (f16*)(pool + 49152);   // [128 c][128 d], 256B pitch, 32 KB
  int tid = threadIdx.x, wave = tid >> 6, lane = tid & 63, hi = lane >> 4, lr = lane & 15;
  int w1m = wave >> 1, w1n = wave & 1;    // 4 d-groups x 2 s-groups
  size_t qrow = (size_t)b * 8192 + i * 512 + st * 64;
  stage_rows128(qp + qrow * 128, 128, sQ, 64, tid, 512);
  floatx4 zero = {0.f, 0.f, 0.f, 0.f};
  floatx4 acc2[2][8];   // [fn s-frag][cf c-frag], partial over this wave's 32 d
  #pragma unroll
  for (int fn = 0; fn < 2; fn++)
    #pragma unroll
    for (int cf = 0; cf < 8; cf++) acc2[fn][cf] = zero;
  for (int slot = 0; slot < 5; slot++) {
    int j = i - 2 + slot;
    if (j < 0 || j > 15) continue;
    #pragma unroll
    for (int dc = 0; dc < 2; dc++) {
      int dchunk = dhalf * 2 + dc;
      // stage K tile [128 d][128 c] and V tile [128 c][128 d]
      const f16* kb = kp + ((size_t)b * 8192 + j * 512 + dchunk * 128) * 128;
      stage_rows128(kb, 128, sK, 128, tid, 512);
      const f16* vb = vT + (size_t)b * 128 * 8192 + (size_t)j * 512 + dchunk * 128;
      stage_rows128(vb, 8192, sV, 128, tid, 512);
      __syncthreads();
      // GEMM1: S^T[d][s] for this wave's 32 d x 32 s, contraction over c=128
      floatx4 acc1[2][2] = {{zero, zero}, {zero, zero}};
      #pragma unroll
      for (int kc = 0; kc < 128; kc += 32) {
        half8 a0 = fragP256(sK, w1m * 32 + lr, kc + hi * 8);
        half8 a1 = fragP256(sK, w1m * 32 + 16 + lr, kc + hi * 8);
        #pragma unroll
        for (int fn = 0; fn < 2; fn++) {
          half8 bq = fragP256(sQ, w1n * 32 + fn * 16 + lr, kc + hi * 8);
          acc1[0][fn] = MFMA16(a0, bq, acc1[0][fn]);
          acc1[1][fn] = MFMA16(a1, bq, acc1[1][fn]);
        }
      }
      // per-row (d) reciprocal denominators
      float rz[2][4];
      {
        size_t zb = (((size_t)(b * 16 + i) * 16 + j) * 512) + dchunk * 128 + w1m * 32;
        #pragma unroll
        for (int fm = 0; fm < 2; fm++)
          #pragma unroll
          for (int jj = 0; jj < 4; jj++)
            rz[fm][jj] = 1.0f / Z[zb + fm * 16 + hi * 4 + jj];
      }
      // E = exp(S)/Z; in-register transpose S^T[d][s] -> A-frag E[s][d] via shfl
      half8 efrag[2];
      #pragma unroll
      for (int fn = 0; fn < 2; fn++) {
        float ev[2][4];
        #pragma unroll
        for (int fm = 0; fm < 2; fm++)
          #pragma unroll
          for (int jj = 0; jj < 4; jj++)
            ev[fm][jj] = exp2f(acc1[fm][fn][jj] * RSL2E) * rz[fm][jj];
        union { f16 h[2]; unsigned u; } t0, t1, t2, t3;
        t0.h[0] = (f16)ev[0][0]; t0.h[1] = (f16)ev[0][1];  // A0: d = hi*4+{0,1}
        t1.h[0] = (f16)ev[0][2]; t1.h[1] = (f16)ev[0][3];  // A1: d = hi*4+{2,3}
        t2.h[0] = (f16)ev[1][0]; t2.h[1] = (f16)ev[1][1];  // B0: d = 16+hi*4+{0,1}
        t3.h[0] = (f16)ev[1][2]; t3.h[1] = (f16)ev[1][3];  // B1
        unsigned A0 = t0.u, A1 = t1.u, B0 = t2.u, B1 = t3.u;
        unsigned pA0 = __shfl_xor((int)A0, 16, 64);
        unsigned pA1 = __shfl_xor((int)A1, 16, 64);
        unsigned pB0 = __shfl_xor((int)B0, 16, 64);
        unsigned pB1 = __shfl_xor((int)B1, 16, 64);
        bool low = (hi & 1) == 0;
        unsigned P[4], Q[4];
        P[0] = low ? A0 : pA0;  P[1] = low ? A1 : pA1;
        P[2] = low ? pA0 : A0;  P[3] = low ? pA1 : A1;
        Q[0] = low ? B0 : pB0;  Q[1] = low ? B1 : pB1;
        Q[2] = low ? pB0 : B0;  Q[3] = low ? pB1 : B1;
        union { unsigned w[4]; half8 h; } outw;
        #pragma unroll
        for (int w = 0; w < 4; w++) {
          unsigned snd = (hi < 2) ? Q[w] : P[w];
          unsigned rcv = __shfl_xor((int)snd, 32, 64);
          outw.w[w] = (hi == 0) ? P[w] : (hi == 3) ? Q[w] : rcv;
        }
        efrag[fn] = outw.h;
      }
      // GEMM2: partial out[s][c] over this wave's 32 d (single K=32 step)
      #pragma unroll
      for (int cf = 0; cf < 8; cf++) {
        half8 vf = fragP256(sV, cf * 16 + lr, w1m * 32 + hi * 8);
        acc2[0][cf] = MFMA16(efrag[0], vf, acc2[0][cf]);
        acc2[1][cf] = MFMA16(efrag[1], vf, acc2[1][cf]);
      }
      __syncthreads();   // all reads done before next stage overwrites sK/sV
    }
  }
  // epilogue: reduce the 4 d-group partials into ef[64 s][128 c]
  float* ef = (float*)(pool + 16384);   // 32 KB, overlays dead sK
  #pragma unroll
  for (int g = 0; g < 4; g++) {
    if (w1m == g) {
      #pragma unroll
      for (int fn = 0; fn < 2; fn++)
        #pragma unroll
        for (int cf = 0; cf < 8; cf++)
          #pragma unroll
          for (int reg = 0; reg < 4; reg++) {
            int s = w1n * 32 + fn * 16 + hi * 4 + reg;
            int c = cf * 16 + lr;
            if (g == 0) ef[s * 128 + c] = acc2[fn][cf][reg];
            else        ef[s * 128 + c] += acc2[fn][cf][reg];
          }
    }
    __syncthreads();
  }
  float* po = Pbuf + ((size_t)((((b * 16 + i) * 8 + st) * 2) + dhalf)) * 8192;
  for (int idx = tid; idx < 2048; idx += 512)
    ((float4*)po)[idx] = ((const float4*)ef)[idx];
}

// ---- reduce the two d-half partials + U -> split attnout ----
__global__ void k_reduceB(const float* __restrict__ Pbuf, const float* __restrict__ U,
                          f16* __restrict__ aoh, f16* __restrict__ aol) {
  int blk = blockIdx.x;   // (b,i,st)
  int b = blk >> 7, i = (blk >> 3) & 15, st = blk & 7;
  int tid = threadIdx.x;
  __shared__ float sU[128];
  if (tid < 128) sU[tid] = U[((size_t)b * 16 + i) * 128 + tid];
  __syncthreads();
  const float4* p0 = (const float4*)(Pbuf + (size_t)blk * 2 * 8192);
  const float4* p1 = p0 + 2048;
  size_t obase = ((size_t)b * 8192 + i * 512 + st * 64) * 128;
  for (int idx = tid; idx < 2048; idx += 256) {
    float4 a = p0[idx], c = p1[idx];
    int cbase = (idx & 31) * 4;
    float vals[4] = {a.x + c.x, a.y + c.y, a.z + c.z, a.w + c.w};
    union { f16 v[4]; uint2 u; } rh, rl;
    for (int t = 0; t < 4; t++) {
      float v = vals[t] + sU[cbase + t];
      split2(v, rh.v[t], rl.v[t]);
    }
    *(uint2*)(aoh + obase + (size_t)idx * 4) = rh.u;
    *(uint2*)(aol + obase + (size_t)idx * 4) = rl.u;
  }
}

extern "C" void kernel_launch(void* const* d_in, const int* in_sizes, int n_in,
                              void* d_out, int out_size, void* d_ws, size_t ws_size,
                              hipStream_t stream) {
  const float* query     = (const float*)d_in[0];
  const float* key_value = (const float*)d_in[1];
  const float* Wq  = (const float*)d_in[2];
  const float* bq  = (const float*)d_in[3];
  const float* Wkv = (const float*)d_in[4];
  const float* bkv = (const float*)d_in[5];
  const float* Wo  = (const float*)d_in[6];
  const float* bo  = (const float*)d_in[7];
  float* out = (float*)d_out;

  char* ws = (char*)d_ws;
  size_t off = 0;
  auto alloc = [&](size_t bytes) -> char* {
    char* p = ws + off;
    off += (bytes + 255) & ~(size_t)255;
    return p;
  };
  const size_t SZH = (size_t)16384 * 128 * 2;   // one f16 array over all rows
  f16* qsh  = (f16*)alloc(SZH); f16* qsl  = (f16*)alloc(SZH);
  f16* kvsh = (f16*)alloc(SZH); f16* kvsl = (f16*)alloc(SZH);
  f16* qhp  = (f16*)alloc(SZH);   // q projected, single f16
  f16* khp  = (f16*)alloc(SZH);   // k projected, single f16
  f16* vT   = (f16*)alloc(SZH);   // v projected, transposed [b][c][l], single f16
  f16* aoh  = (f16*)alloc(SZH); f16* aol  = (f16*)alloc(SZH);
  f16* WqTh  = (f16*)alloc(32768); f16* WqTl  = (f16*)alloc(32768);
  f16* WkvTh = (f16*)alloc(65536); f16* WkvTl = (f16*)alloc(65536);
  f16* WoTh  = (f16*)alloc(32768); f16* WoTl  = (f16*)alloc(32768);
  float* Zb = (float*)alloc((size_t)2 * 16 * 16 * 512 * 4);
  float* Ub = (float*)alloc((size_t)2 * 16 * 128 * 4);
  if (off > ws_size) return;   // workspace too small: bail (output stays zero -> visible failure)
  // Pbuf (16.78 MB) aliases qsh/qsl/kvsh/kvsl — dead after the k_proj launches.
  float* Pbuf = (float*)ws;

  k_splitW<<<256, 256, 0, stream>>>(Wq, Wkv, Wo, WqTh, WqTl, WkvTh, WkvTl, WoTh, WoTl);
  k_split<<<2048, 256, 0, stream>>>((const float4*)query, (uint2*)qsh, (uint2*)qsl, 524288);
  k_split<<<2048, 256, 0, stream>>>((const float4*)key_value, (uint2*)kvsh, (uint2*)kvsl, 524288);
  // q projection
  k_proj<<<256, 512, 0, stream>>>(qsh, qsl, WqTh, WqTl, bq, qhp, 0);
  // k projection (first 128 channels of Wkv)
  k_proj<<<256, 512, 0, stream>>>(kvsh, kvsl, WkvTh, WkvTl, bkv, khp, 0);
  // v projection (second 128 channels), stored transposed [b][c][l]
  k_proj<<<256, 512, 0, stream>>>(kvsh, kvsl, WkvTh + 128 * 128, WkvTl + 128 * 128,
                                  bkv + 128, vT, 1);
  k_U<<<256, 256, 0, stream>>>(vT, Ub);
  k_passA<<<640, 512, 0, stream>>>(khp, qhp, Zb);
  k_passB<<<512, 512, 0, stream>>>(qhp, khp, vT, Zb, Pbuf);
  k_reduceB<<<256, 256, 0, stream>>>(Pbuf, Ub, aoh, aol);
  k_final<<<256, 512, 0, stream>>>(aoh, aol, WoTh, WoTl, bo, out);
}